// Round 6
// baseline (297.893 us; speedup 1.0000x reference)
//
#include <hip/hip_runtime.h>

// Linear(int8-weight, block-sparse) -> quantize -> dequantize, as one fp16 MFMA GEMM.
// out[n,o] = dq(q( (x @ (w_q*mask)^T) * w_scale + bias ))
// N=8192 tokens, O=4096, K=4096.
//
// Numerics: w_q*mask are integers in [-127,127] -> exact in fp16; x->fp16
// rounding error << out_scale quant step (validated: absmax 0.0625).
//
// GEMM: 256x256, BK=64, 8 waves (2Mx4N), fragment-pipelined 4-phase K-loop.
// This revision: ROTATED STAGE SCHEDULE. Same 2-load-per-phase spread
// (round 4 proved 4-load bursts regress), but each pane now staged 2-3
// phases before its publish instead of 1-2.5:
//   P1(s): B_k0(s+1)  -> published end-P3(s)   [2 phases]
//   P2(s): A_k1(s+1)  -> published end-P1(s+1) [3 phases]
//   P3(s): B_k1(s+1)  -> published end-P1(s+1) [2 phases]
//   P4(s): A_k0(s+2)  -> published end-P3(s+1) [3 phases]  (current buf: pane dead after P1(s))
// Issue-order arithmetic: 8 loads outstanding at each publish, oldest 4 are
// the published group -> uniform VMCNT(4); VMCNT(0) only at the final publish.
// Pane WAR hazards: every pane's last consumer is >=2 barriers before its
// re-stage (checked per-pane; reads are lgkm-drained one phase after issue).
// T2 granule-XOR swizzle keeps ds_read conflict-free (rounds 2-5: 0 conflicts).

#define M_TOK 8192
#define O_FEAT 4096
#define K_FEAT 4096

#define BM 256
#define BN 256
#define BK 64
#define NT (K_FEAT / BK)   // 64 K-tiles

// LDS element strides for smem[2][2][2][BM*32]: buf=32768, mat=16384, kh=8192
#define S_BUF 32768
#define S_MAT 16384
#define S_KH  8192

using f16x8 = __attribute__((ext_vector_type(8))) _Float16;
using f32x4 = __attribute__((ext_vector_type(4))) float;

#define BAR()    asm volatile("s_barrier" ::: "memory")
#define VMCNT(n) asm volatile("s_waitcnt vmcnt(" #n ")" ::: "memory")
#define MFMA16(a, b, c) __builtin_amdgcn_mfma_f32_16x16x32_f16((a), (b), (c), 0, 0, 0)

// ---------------- fp32 -> fp16 conversion of activations ----------------
__global__ __launch_bounds__(256) void cvt_x_kernel(const float* __restrict__ x,
                                                    _Float16* __restrict__ xf) {
    size_t i = ((size_t)blockIdx.x * 256 + threadIdx.x) * 8;
    float4 v0 = *reinterpret_cast<const float4*>(x + i);
    float4 v1 = *reinterpret_cast<const float4*>(x + i + 4);
    f16x8 h;
    h[0] = (_Float16)v0.x; h[1] = (_Float16)v0.y;
    h[2] = (_Float16)v0.z; h[3] = (_Float16)v0.w;
    h[4] = (_Float16)v1.x; h[5] = (_Float16)v1.y;
    h[6] = (_Float16)v1.z; h[7] = (_Float16)v1.w;
    *reinterpret_cast<f16x8*>(xf + i) = h;
}

// ------------- fuse block mask into fp16 weights (exact ints) -----------
__global__ __launch_bounds__(256) void cvt_w_kernel(const float* __restrict__ wq,
                                                    const int* __restrict__ mask,
                                                    _Float16* __restrict__ wf) {
    size_t i = ((size_t)blockIdx.x * 256 + threadIdx.x) * 8;  // 8 weights = 2 mask blocks
    float4 v0 = *reinterpret_cast<const float4*>(wq + i);
    float4 v1 = *reinterpret_cast<const float4*>(wq + i + 4);
    int2 mv = *reinterpret_cast<const int2*>(mask + i / 4);
    float m0 = mv.x ? 1.0f : 0.0f;
    float m1 = mv.y ? 1.0f : 0.0f;
    f16x8 h;
    h[0] = (_Float16)(v0.x * m0); h[1] = (_Float16)(v0.y * m0);
    h[2] = (_Float16)(v0.z * m0); h[3] = (_Float16)(v0.w * m0);
    h[4] = (_Float16)(v1.x * m1); h[5] = (_Float16)(v1.y * m1);
    h[6] = (_Float16)(v1.z * m1); h[7] = (_Float16)(v1.w * m1);
    *reinterpret_cast<f16x8*>(wf + i) = h;
}

// ---------------- 256x256 fragment-pipelined fp16 MFMA GEMM -------------
// A [8192][4096] f16 row-major, B [4096][4096] f16 row-major (B^T GEMM).
// Swizzle: 16B granule kq -> kq ^ ((row>>1)&3); linear LDS dest +
// inverse-permuted global src (global_load_lds), same XOR on ds_read.
__global__ __launch_bounds__(512, 2) void gemm_kernel(const _Float16* __restrict__ A,
                                                      const _Float16* __restrict__ B,
                                                      const float* __restrict__ bias,
                                                      const float* __restrict__ wsp,
                                                      const float* __restrict__ osp,
                                                      float* __restrict__ C) {
    __shared__ __align__(16) _Float16 smem[2][2][2][BM * 32];
    _Float16* sm = &smem[0][0][0][0];

    const int tid  = threadIdx.x;
    const int lane = tid & 63;
    const int w    = tid >> 6;      // 0..7
    const int wm   = w >> 2;        // 0..1  (M half)
    const int wn   = w & 3;         // 0..3  (N quarter)
    const int lr   = lane & 15;     // fragment row/col
    const int kq   = lane >> 4;     // 0..3  k-granule

    const int bm = blockIdx.x >> 4; // 32 M-tiles
    const int bn = blockIdx.x & 15; // 16 N-tiles

    // ---- staging geometry (hoisted advancing pointers) ----
    const int sr0  = w * 32 + (lane >> 2);
    const int csrc = ((lane & 3) ^ ((lane >> 3) & 3)) * 8;  // inverse-swizzled src granule
    const size_t J1 = (size_t)16 * K_FEAT;                  // j=1 source row offset

    const _Float16* pA0 = A + (size_t)(bm * BM + sr0) * K_FEAT + csrc;  // A kh0
    const _Float16* pA1 = pA0 + 32;                                      // A kh1
    const _Float16* pB0 = B + (size_t)(bn * BN + sr0) * K_FEAT + csrc;  // B kh0
    const _Float16* pB1 = pB0 + 32;                                      // B kh1

    const int dst0 = (w * 128 + lane) * 8;   // j=0 LDS dst elem offset within a pane
    const int dst1 = dst0 + 64 * 8;          // j=1

    auto stg = [&](const _Float16* src, _Float16* dstp) {
        __builtin_amdgcn_global_load_lds(
            (const __attribute__((address_space(1))) void*)(const void*)src,
            (__attribute__((address_space(3))) void*)(void*)dstp, 16, 0, 0);
    };

    // ---- fragment read offsets (hoisted, swizzled) ----
    int offA[4], offB[4];
#pragma unroll
    for (int m = 0; m < 4; ++m) {
        const int r = wm * 128 + m * 16 + lr;
        offA[m] = r * 32 + ((kq ^ ((r >> 1) & 3)) << 3);
    }
#pragma unroll
    for (int n = 0; n < 4; ++n) {
        const int r = wn * 64 + n * 16 + lr;
        offB[n] = r * 32 + ((kq ^ ((r >> 1) & 3)) << 3);
    }
    auto rd = [&](const _Float16* sbuf, int off, int immE) -> f16x8 {
        return *reinterpret_cast<const f16x8*>(sbuf + off + immE);  // immE folds into ds offset
    };

    f32x4 acc[8][4] = {};
    f16x8 a0[4], a1[4], b0v[4], b1v[4];

    // ---- prologue ----
    // G1..G5 (2 loads each): A_k0(0), B_k0(0), A_k1(0), B_k1(0) -> buf0; A_k0(1) -> buf1.
    // VMCNT(6): G1,G2 (kh0(0)) landed; prime P1 fragments.
    stg(pA0, sm + dst0);                    stg(pA0 + J1, sm + dst1);
    stg(pB0, sm + S_MAT + dst0);            stg(pB0 + J1, sm + S_MAT + dst1);
    stg(pA1, sm + S_KH + dst0);             stg(pA1 + J1, sm + S_KH + dst1);
    stg(pB1, sm + S_MAT + S_KH + dst0);     stg(pB1 + J1, sm + S_MAT + S_KH + dst1);
    stg(pA0 + BK, sm + S_BUF + dst0);       stg(pA0 + BK + J1, sm + S_BUF + dst1);
    VMCNT(6);
    BAR();
#pragma unroll
    for (int m = 0; m < 4; ++m) a0[m] = rd(sm, offA[m], 0);
#pragma unroll
    for (int n = 0; n < 4; ++n) b0v[n] = rd(sm, offB[n], S_MAT);
    // pointer targets after prologue: pB0/pA1/pB1 -> t=1 (P1/P2/P3 stages), pA0 -> t=2 (P4 stage)
    pA0 += 2 * BK; pA1 += BK; pB0 += BK; pB1 += BK;

    for (int s = 0; s < NT; ++s) {
        const _Float16* sb = sm + ((s & 1) ? S_BUF : 0);   // current buf
        _Float16*       sn = sm + ((s & 1) ? 0 : S_BUF);   // next buf
        const bool more = (s + 1 < NT);

        // ---- P1: read a47_k0; stage B_k0(s+1); MFMA m0-3 x kh0 ----
#pragma unroll
        for (int m = 0; m < 4; ++m) a1[m] = rd(sb, offA[m], 2048);
        if (more) { stg(pB0, sn + S_MAT + dst0); stg(pB0 + J1, sn + S_MAT + dst1); }
        BAR();
        __builtin_amdgcn_s_setprio(1);
#pragma unroll
        for (int m = 0; m < 4; ++m)
#pragma unroll
            for (int n = 0; n < 4; ++n)
                acc[m][n] = MFMA16(a0[m], b0v[n], acc[m][n]);
        __builtin_amdgcn_s_setprio(0);
        // publish kh1(s): A_k1(s)[P2(s-1)], B_k1(s)[P3(s-1)] are the oldest 4
        // of 8 outstanding loads -> VMCNT(4). Last tile: nothing behind -> 0.
        if (s == NT - 1) { VMCNT(0); } else { VMCNT(4); }
        BAR();

        // ---- P2: read a03_k1 + b_k1; stage A_k1(s+1); MFMA m4-7 x kh0 ----
#pragma unroll
        for (int m = 0; m < 4; ++m) a0[m] = rd(sb, offA[m], S_KH);
#pragma unroll
        for (int n = 0; n < 4; ++n) b1v[n] = rd(sb, offB[n], S_MAT + S_KH);
        if (more) { stg(pA1, sn + S_KH + dst0); stg(pA1 + J1, sn + S_KH + dst1); }
        BAR();
        __builtin_amdgcn_s_setprio(1);
#pragma unroll
        for (int m = 0; m < 4; ++m)
#pragma unroll
            for (int n = 0; n < 4; ++n)
                acc[4 + m][n] = MFMA16(a1[m], b0v[n], acc[4 + m][n]);
        __builtin_amdgcn_s_setprio(0);

        // ---- P3: read a47_k1; stage B_k1(s+1); MFMA m0-3 x kh1 ----
#pragma unroll
        for (int m = 0; m < 4; ++m) a1[m] = rd(sb, offA[m], S_KH + 2048);
        if (more) { stg(pB1, sn + S_MAT + S_KH + dst0); stg(pB1 + J1, sn + S_MAT + S_KH + dst1); }
        BAR();
        __builtin_amdgcn_s_setprio(1);
#pragma unroll
        for (int m = 0; m < 4; ++m)
#pragma unroll
            for (int n = 0; n < 4; ++n)
                acc[m][n] = MFMA16(a0[m], b1v[n], acc[m][n]);
        __builtin_amdgcn_s_setprio(0);
        // publish kh0(s+1): A_k0(s+1)[P4(s-1)], B_k0(s+1)[P1(s)] are the oldest 4
        // of 8 outstanding -> VMCNT(4).
        if (more) { VMCNT(4); BAR(); }

        // ---- P4: read next-tile a03_k0 + b_k0; stage A_k0(s+2) into CURRENT buf; MFMA m4-7 x kh1 ----
        if (s + 2 < NT) {
            // sb.A_k0 pane (holding A_k0(s)) is dead: last consumer was P2(s)'s MFMA,
            // separated from here by the end-P3 publish barrier + P4 pre-barrier.
            stg(pA0, const_cast<_Float16*>(sb) + dst0);
            stg(pA0 + J1, const_cast<_Float16*>(sb) + dst1);
        }
        if (more) {
#pragma unroll
            for (int m = 0; m < 4; ++m) a0[m] = rd(sn, offA[m], 0);
#pragma unroll
            for (int n = 0; n < 4; ++n) b0v[n] = rd(sn, offB[n], S_MAT);
            pA0 += BK; pA1 += BK; pB0 += BK; pB1 += BK;
        }
        BAR();
        __builtin_amdgcn_s_setprio(1);
#pragma unroll
        for (int m = 0; m < 4; ++m)
#pragma unroll
            for (int n = 0; n < 4; ++n)
                acc[4 + m][n] = MFMA16(a1[m], b1v[n], acc[4 + m][n]);
        __builtin_amdgcn_s_setprio(0);
    }

    // ---------------- fused epilogue: scale + bias + quant + dequant ----
    const float wscale = wsp[0];
    const float oscale = osp[0];
    const int row0 = bm * BM + wm * 128;
    const int col0 = bn * BN + wn * 64;
#pragma unroll
    for (int n = 0; n < 4; ++n) {
        const int col = col0 + n * 16 + lr;
        const float bc = bias[col];
#pragma unroll
        for (int m = 0; m < 8; ++m) {
#pragma unroll
            for (int j = 0; j < 4; ++j) {
                const int row = row0 + m * 16 + kq * 4 + j;
                float y = acc[m][n][j] * wscale + bc;
                float q = rintf(y / oscale);          // round-half-even, matches jnp.round
                q = fminf(fmaxf(q, -128.0f), 127.0f);
                C[(size_t)row * O_FEAT + col] = q * oscale;
            }
        }
    }
}

extern "C" void kernel_launch(void* const* d_in, const int* in_sizes, int n_in,
                              void* d_out, int out_size, void* d_ws, size_t ws_size,
                              hipStream_t stream) {
    const float* x        = (const float*)d_in[0];  // [8192,4096] fp32
    const float* wq       = (const float*)d_in[1];  // [4096,4096] fp32 (int8 values)
    const float* bias     = (const float*)d_in[2];  // [4096]
    const float* w_scale  = (const float*)d_in[3];  // scalar
    const float* out_scale= (const float*)d_in[4];  // scalar
    const int*   mask     = (const int*)d_in[5];    // [4096,1024] int32
    float* out = (float*)d_out;

    _Float16* xf = (_Float16*)d_ws;                                        // 64 MiB
    _Float16* wf = (_Float16*)((char*)d_ws + (size_t)M_TOK * K_FEAT * 2);  // +32 MiB

    cvt_x_kernel<<<(M_TOK * (size_t)K_FEAT) / 8 / 256, 256, 0, stream>>>(x, xf);
    cvt_w_kernel<<<(O_FEAT * (size_t)K_FEAT) / 8 / 256, 256, 0, stream>>>(wq, mask, wf);

    // (8192/256) x (4096/256) = 32*16 = 512 blocks, 512 threads
    gemm_kernel<<<dim3((M_TOK / BM) * (O_FEAT / BN)), 512, 0, stream>>>(
        xf, wf, bias, w_scale, out_scale, out);
}

// Round 7
// 286.715 us; speedup vs baseline: 1.0390x; 1.0390x over previous
//
#include <hip/hip_runtime.h>

// Linear(int8-weight, block-sparse) -> quantize -> dequantize, as one fp16 MFMA GEMM.
// out[n,o] = dq(q( (x @ (w_q*mask)^T) * w_scale + bias ))
// N=8192 tokens, O=4096, K=4096.
//
// Numerics: w_q*mask are integers in [-127,127] -> exact in fp16; x->fp16
// rounding error << out_scale quant step (validated: absmax 0.0625).
//
// GEMM: faithful m201 8-phase skeleton (2 K-tiles per iteration).
// LDS panes [mat][buf][mhalf][128x64] f16 (128 KiB). Per phase:
//   {ds-reads for THIS phase's 16-MFMA quadrant; stage 1 pane (2 gloads);
//    [lgkmcnt(8) if 12 reads]; s_barrier; lgkmcnt(0); setprio(1);
//    16 MFMA; setprio(0); s_barrier}
// VMCNT(2) only at phases 4 and 8 (one publish per K-tile).
// Quadrant order (m03,n01)->(m03,n23)->(m47,n23)->(m47,n01): <=16 live b128.
// Swizzle (128 B rows): 16B-granule g -> g ^ (row&7); row&7==lr&7 so the
// term folds into per-thread read bases; stage source pre-permuted with
// gs = (tid&7)^((tid>>3)&7) (linear LDS dst, rule both-sides-or-neither).
// Stage->pane WAR: each pane's last reader finishes >=1 closing barrier
// before its re-stage (map: c1 A(s1,mh1)->b1, c2 B(s1,mh0), c3 B(s1,mh1),
// c4 A(s0+2,mh0)->b0, c5 A(s0+2,mh1), c6 B(s0+2,mh0), c7 B(s0+2,mh1),
// c8 A(s0+3,mh0)->b1).

#define M_TOK 8192
#define O_FEAT 4096
#define K_FEAT 4096

#define BM 256
#define BN 256
#define NITER 32            // 64 K-tiles, 2 per iteration

using f16x8 = __attribute__((ext_vector_type(8))) _Float16;
using f32x4 = __attribute__((ext_vector_type(4))) float;

#define BAR()    asm volatile("s_barrier" ::: "memory")
#define LGKM0()  asm volatile("s_waitcnt lgkmcnt(0)" ::: "memory")
#define LGKM8()  asm volatile("s_waitcnt lgkmcnt(8)" ::: "memory")
#define VMCNT(n) asm volatile("s_waitcnt vmcnt(" #n ")" ::: "memory")
#define MFMA16(a, b, c) __builtin_amdgcn_mfma_f32_16x16x32_f16((a), (b), (c), 0, 0, 0)

// ---------------- fp32 -> fp16 conversion of activations ----------------
__global__ __launch_bounds__(256) void cvt_x_kernel(const float* __restrict__ x,
                                                    _Float16* __restrict__ xf) {
    size_t i = ((size_t)blockIdx.x * 256 + threadIdx.x) * 8;
    float4 v0 = *reinterpret_cast<const float4*>(x + i);
    float4 v1 = *reinterpret_cast<const float4*>(x + i + 4);
    f16x8 h;
    h[0] = (_Float16)v0.x; h[1] = (_Float16)v0.y;
    h[2] = (_Float16)v0.z; h[3] = (_Float16)v0.w;
    h[4] = (_Float16)v1.x; h[5] = (_Float16)v1.y;
    h[6] = (_Float16)v1.z; h[7] = (_Float16)v1.w;
    *reinterpret_cast<f16x8*>(xf + i) = h;
}

// ------------- fuse block mask into fp16 weights (exact ints) -----------
__global__ __launch_bounds__(256) void cvt_w_kernel(const float* __restrict__ wq,
                                                    const int* __restrict__ mask,
                                                    _Float16* __restrict__ wf) {
    size_t i = ((size_t)blockIdx.x * 256 + threadIdx.x) * 8;  // 8 weights = 2 mask blocks
    float4 v0 = *reinterpret_cast<const float4*>(wq + i);
    float4 v1 = *reinterpret_cast<const float4*>(wq + i + 4);
    int2 mv = *reinterpret_cast<const int2*>(mask + i / 4);
    float m0 = mv.x ? 1.0f : 0.0f;
    float m1 = mv.y ? 1.0f : 0.0f;
    f16x8 h;
    h[0] = (_Float16)(v0.x * m0); h[1] = (_Float16)(v0.y * m0);
    h[2] = (_Float16)(v0.z * m0); h[3] = (_Float16)(v0.w * m0);
    h[4] = (_Float16)(v1.x * m1); h[5] = (_Float16)(v1.y * m1);
    h[6] = (_Float16)(v1.z * m1); h[7] = (_Float16)(v1.w * m1);
    *reinterpret_cast<f16x8*>(wf + i) = h;
}

// ---------------- 256x256 8-phase fp16 MFMA GEMM ------------------------
// A [8192][4096] f16 row-major, B [4096][4096] f16 row-major (B^T GEMM).
// LDS byte layout: mat*65536 + buf*32768 + mhalf*16384 + row*128 + swz(col).
__global__ __launch_bounds__(512, 2) void gemm_kernel(const _Float16* __restrict__ A,
                                                      const _Float16* __restrict__ B,
                                                      const float* __restrict__ bias,
                                                      const float* __restrict__ wsp,
                                                      const float* __restrict__ osp,
                                                      float* __restrict__ C) {
    __shared__ __align__(16) unsigned char smem[131072];
    char* smc = (char*)smem;

    const int tid  = threadIdx.x;
    const int lane = tid & 63;
    const int w    = tid >> 6;      // 0..7
    const int wm   = w >> 2;        // 0..1  (M half)
    const int wn   = w & 3;         // 0..3  (N quarter)
    const int lr   = lane & 15;     // fragment row/col
    const int kq   = lane >> 4;     // 0..3  k-granule

    const int bm = blockIdx.x >> 4; // 32 M-tiles
    const int bn = blockIdx.x & 15; // 16 N-tiles

    // ---- read bases (swizzled, per-thread; kh flips byte-bit6) ----
    const int laneSwz = lr * 128 + ((kq ^ (lr & 3)) << 4) + (((lr >> 2) & 1) << 6);
    const char* aK0 = smc + wm * 16384 + laneSwz;
    const char* aK1 = smc + wm * 16384 + (laneSwz ^ 64);
    const char* bK0 = smc + 65536 + (wn >> 1) * 16384 + (wn & 1) * 8192 + laneSwz;
    const char* bK1 = smc + 65536 + (wn >> 1) * 16384 + (wn & 1) * 8192 + (laneSwz ^ 64);

    // ---- stage geometry: linear LDS dst, inverse-swizzled global src ----
    const int gs = (tid & 7) ^ ((tid >> 3) & 7);   // source 16B granule
    const _Float16* pAsrc = A + (size_t)(bm * BM + (tid >> 3)) * K_FEAT + gs * 8;
    const _Float16* pBsrc = B + (size_t)(bn * BN + (tid >> 3)) * K_FEAT + gs * 8;
    char* dstT = smc + tid * 16;

    auto gload = [&](const _Float16* src, char* dst) {
        __builtin_amdgcn_global_load_lds(
            (const __attribute__((address_space(1))) void*)(const void*)src,
            (__attribute__((address_space(3))) void*)(void*)dst, 16, 0, 0);
    };
    auto stgA = [&](int buf, int mh, int kElem) {   // one A pane = 2 gloads
#pragma unroll
        for (int j = 0; j < 2; ++j)
            gload(pAsrc + (size_t)(mh * 128 + j * 64) * K_FEAT + kElem,
                  dstT + buf * 32768 + mh * 16384 + j * 8192);
    };
    auto stgB = [&](int buf, int mh, int kElem) {   // one B pane = 2 gloads
#pragma unroll
        for (int j = 0; j < 2; ++j)
            gload(pBsrc + (size_t)(mh * 128 + j * 64) * K_FEAT + kElem,
                  dstT + 65536 + buf * 32768 + mh * 16384 + j * 8192);
    };

    auto rdA = [&](int m, int kh, int buf) -> f16x8 {
        return *reinterpret_cast<const f16x8*>((kh ? aK1 : aK0) + buf * 32768 + m * 2048);
    };
    auto rdB = [&](int n, int kh, int buf) -> f16x8 {
        return *reinterpret_cast<const f16x8*>((kh ? bK1 : bK0) + buf * 32768 + n * 2048);
    };

    f32x4 acc[8][4] = {};
    f16x8 aR[8], bA[4], bB[4];

#define RD_A(MB, BUF) _Pragma("unroll") for (int kh = 0; kh < 2; ++kh) \
    _Pragma("unroll") for (int mi = 0; mi < 4; ++mi) aR[kh * 4 + mi] = rdA((MB) + mi, kh, BUF)
#define RD_BV(DST, NB, BUF) _Pragma("unroll") for (int kh = 0; kh < 2; ++kh) \
    _Pragma("unroll") for (int ni = 0; ni < 2; ++ni) DST[kh * 2 + ni] = rdB((NB) + ni, kh, BUF)
#define QUAD(MS, NS, BV) do { _Pragma("unroll") for (int kh = 0; kh < 2; ++kh) \
    _Pragma("unroll") for (int mi = 0; mi < 4; ++mi) \
    _Pragma("unroll") for (int ni = 0; ni < 2; ++ni) \
        acc[(MS) * 4 + mi][(NS) * 2 + ni] = \
            MFMA16(aR[kh * 4 + mi], BV[kh * 2 + ni], acc[(MS) * 4 + mi][(NS) * 2 + ni]); } while (0)
#define PRIO1() __builtin_amdgcn_s_setprio(1)
#define PRIO0() __builtin_amdgcn_s_setprio(0)

    // ---- prologue: K-tile0 panes (8 loads) + A(1,mh0) (2) ----
    stgA(0, 0, 0); stgA(0, 1, 0); stgB(0, 0, 0); stgB(0, 1, 0);
    stgA(1, 0, 64);
    VMCNT(2);       // K-tile0 landed; A(1,mh0) in flight
    BAR();

    size_t kOff = 0;     // elem K-offset of s0 = 2t
    for (int t = 0; t < NITER; ++t) {
        const bool more = (t + 1 < NITER);

        // ================= K-tile s0 (buf 0) =================
        // c1: 12 reads; stage A(s1,mh1)->b1
        RD_A(0, 0); RD_BV(bA, 0, 0);
        stgA(1, 1, kOff + 64);
        LGKM8(); BAR(); LGKM0();
        PRIO1(); QUAD(0, 0, bA); PRIO0(); BAR();

        // c2: 4 reads; stage B(s1,mh0)->b1
        RD_BV(bB, 2, 0);
        stgB(1, 0, kOff + 64);
        BAR(); LGKM0();
        PRIO1(); QUAD(0, 1, bB); PRIO0(); BAR();

        // c3: 8 reads; stage B(s1,mh1)->b1
        RD_A(4, 0);
        stgB(1, 1, kOff + 64);
        BAR(); LGKM0();
        PRIO1(); QUAD(1, 1, bB); PRIO0(); BAR();

        // c4: 4 reads; stage A(s0+2,mh0)->b0; publish s1
        RD_BV(bA, 0, 0);
        if (more) stgA(0, 0, kOff + 128);
        BAR(); LGKM0();
        PRIO1(); QUAD(1, 0, bA); PRIO0();
        if (more) { VMCNT(2); } else { VMCNT(0); }
        BAR();

        // ================= K-tile s1 (buf 1) =================
        // c5: 12 reads; stage A(s0+2,mh1)->b0
        RD_A(0, 1); RD_BV(bA, 0, 1);
        if (more) stgA(0, 1, kOff + 128);
        LGKM8(); BAR(); LGKM0();
        PRIO1(); QUAD(0, 0, bA); PRIO0(); BAR();

        // c6: 4 reads; stage B(s0+2,mh0)->b0
        RD_BV(bB, 2, 1);
        if (more) stgB(0, 0, kOff + 128);
        BAR(); LGKM0();
        PRIO1(); QUAD(0, 1, bB); PRIO0(); BAR();

        // c7: 8 reads; stage B(s0+2,mh1)->b0
        RD_A(4, 1);
        if (more) stgB(0, 1, kOff + 128);
        BAR(); LGKM0();
        PRIO1(); QUAD(1, 1, bB); PRIO0(); BAR();

        // c8: 4 reads; stage A(s0+3,mh0)->b1; publish s0+2
        RD_BV(bA, 0, 1);
        if (more) stgA(1, 0, kOff + 192);
        BAR(); LGKM0();
        PRIO1(); QUAD(1, 0, bA); PRIO0();
        if (more) { VMCNT(2); }
        BAR();

        kOff += 128;
    }

    // ---------------- fused epilogue: scale + bias + quant + dequant ----
    const float wscale = wsp[0];
    const float oscale = osp[0];
    const int row0 = bm * BM + wm * 128;
    const int col0 = bn * BN + wn * 64;
#pragma unroll
    for (int n = 0; n < 4; ++n) {
        const int col = col0 + n * 16 + lr;
        const float bc = bias[col];
#pragma unroll
        for (int m = 0; m < 8; ++m) {
#pragma unroll
            for (int j = 0; j < 4; ++j) {
                const int row = row0 + m * 16 + kq * 4 + j;
                float y = acc[m][n][j] * wscale + bc;
                float q = rintf(y / oscale);          // round-half-even, matches jnp.round
                q = fminf(fmaxf(q, -128.0f), 127.0f);
                C[(size_t)row * O_FEAT + col] = q * oscale;
            }
        }
    }
#undef RD_A
#undef RD_BV
#undef QUAD
#undef PRIO1
#undef PRIO0
}

extern "C" void kernel_launch(void* const* d_in, const int* in_sizes, int n_in,
                              void* d_out, int out_size, void* d_ws, size_t ws_size,
                              hipStream_t stream) {
    const float* x        = (const float*)d_in[0];  // [8192,4096] fp32
    const float* wq       = (const float*)d_in[1];  // [4096,4096] fp32 (int8 values)
    const float* bias     = (const float*)d_in[2];  // [4096]
    const float* w_scale  = (const float*)d_in[3];  // scalar
    const float* out_scale= (const float*)d_in[4];  // scalar
    const int*   mask     = (const int*)d_in[5];    // [4096,1024] int32
    float* out = (float*)d_out;

    _Float16* xf = (_Float16*)d_ws;                                        // 64 MiB
    _Float16* wf = (_Float16*)((char*)d_ws + (size_t)M_TOK * K_FEAT * 2);  // +32 MiB

    cvt_x_kernel<<<(M_TOK * (size_t)K_FEAT) / 8 / 256, 256, 0, stream>>>(x, xf);
    cvt_w_kernel<<<(O_FEAT * (size_t)K_FEAT) / 8 / 256, 256, 0, stream>>>(wq, mask, wf);

    // (8192/256) x (4096/256) = 32*16 = 512 blocks, 512 threads
    gemm_kernel<<<dim3((M_TOK / BM) * (O_FEAT / BN)), 512, 0, stream>>>(
        xf, wf, bias, w_scale, out_scale, out);
}